// Round 4
// baseline (673.174 us; speedup 1.0000x reference)
//
#include <hip/hip_runtime.h>

// BertEmbedding + 5-layer GAT on MI355X (gfx950). Robust round: runtime
// dtype detection (f32-vs-bf16 floats, int64-vs-int32 ints), because two
// structurally different bf16-assuming kernels both produced NaN. All
// layer offsets are computed in ELEMENTS inside kernels (host cannot know
// the element size). Internal compute all f32. Workspace ~3.9 MB.

#define DEV __device__ __forceinline__

DEV float b2f(unsigned int u) { union { unsigned int i; float f; } v; v.i = u << 16; return v.f; }
DEV unsigned short f2b(float f) {
  union { float f; unsigned int i; } v; v.f = f;
  return (unsigned short)((v.i + 0x7fffu + ((v.i >> 16) & 1u)) >> 16);
}
DEV float gelu_exact(float x) { return 0.5f * x * (1.f + erff(x * 0.70710678118654752f)); }

// dual-dtype loads. fF: floats are f32 (else bf16). fI: ints are int64
// (little-endian low word; all values small non-negative) else int32.
DEV float ldf(const void* p, size_t i, int fF) {
  return fF ? ((const float*)p)[i] : b2f(((const unsigned short*)p)[i]);
}
DEV int ldi(const void* p, size_t i, int fI) {
  return fI ? ((const int*)p)[2 * i] : ((const int*)p)[i];
}

// ---------------------------------------------------------------------------
// k_detect: flags[0]=1 iff float tables are f32; flags[1]=1 iff ints are
// int64. bf16 view of an f32 gaussian table shows wild exponents in ~half
// the half-words; a true bf16 *0.02 table never does. pos row0 = arange:
// int32 view element [1] is 1 for int32 data, 0 for int64.
// ---------------------------------------------------------------------------
__global__ __launch_bounds__(64) void k_detect(const unsigned short* __restrict__ word,
                                               const int* __restrict__ pos,
                                               int* __restrict__ flags) {
  if (threadIdx.x == 0) {
    int crazy = 0;
    for (int i = 0; i < 512; ++i) {
      unsigned int e = (word[i] >> 7) & 0xffu;  // bf16 exponent field
      if (e >= 135u || (e >= 1u && e <= 100u)) crazy++;
    }
    flags[0] = (crazy >= 8) ? 1 : 0;
    flags[1] = (pos[1] == 0) ? 1 : 0;
  }
}

// ---------------------------------------------------------------------------
// k_fold: F[l][j][k] (f32) = folded attention columns.
//   j 0..3: sum_d W[l][k][j*192+d]*a_src[l][j][d];  j 4..7: same with a_dst.
// 15 blocks = 5 layers x 3 chunks of 256 k-values.
// ---------------------------------------------------------------------------
__global__ __launch_bounds__(256) void k_fold(const void* __restrict__ Wg,
                                              const void* __restrict__ aS,
                                              const void* __restrict__ aD,
                                              const int* __restrict__ flg,
                                              float* __restrict__ F) {
  int fF = flg[0];
  __shared__ float sA[768], sD[768];
  int l = blockIdx.x / 3, sub = blockIdx.x % 3, t = threadIdx.x;
  for (int i = t; i < 768; i += 256) {
    sA[i] = ldf(aS, (size_t)l * 768 + i, fF);
    sD[i] = ldf(aD, (size_t)l * 768 + i, fF);
  }
  __syncthreads();
  int k = sub * 256 + t;
  size_t wbase = ((size_t)l * 768 + k) * 768;
  float accS[4] = {0.f, 0.f, 0.f, 0.f}, accD[4] = {0.f, 0.f, 0.f, 0.f};
  for (int h = 0; h < 4; ++h)
    for (int dd = 0; dd < 192; ++dd) {
      int d = h * 192 + dd;
      float w = ldf(Wg, wbase + d, fF);
      accS[h] += w * sA[d];
      accD[h] += w * sD[d];
    }
  float* Fl = F + (size_t)l * 8 * 768;
#pragma unroll
  for (int hh = 0; hh < 4; ++hh) {
    Fl[(size_t)hh * 768 + k] = accS[hh];
    Fl[(size_t)(4 + hh) * 768 + k] = accD[hh];
  }
}

// ---------------------------------------------------------------------------
// k_nodes: node 0 of each example = CLS word emb; nodes 1..8 = inclusive
// span sums. Writes f32 x. 576 blocks x 256 thr, 3 features/thread.
// ---------------------------------------------------------------------------
__global__ __launch_bounds__(256) void k_nodes(const void* __restrict__ src,
                                               const void* __restrict__ sst,
                                               const void* __restrict__ sen,
                                               const void* __restrict__ word,
                                               const int* __restrict__ flg,
                                               float* __restrict__ x) {
  int fF = flg[0], fI = flg[1];
  int g = blockIdx.x, t = threadIdx.x;
  int b = g / 9, j = g % 9;
  float v[3] = {0.f, 0.f, 0.f};
  if (j == 0) {
    int r = ldi(src, (size_t)b * 512, fI);
#pragma unroll
    for (int ii = 0; ii < 3; ++ii) v[ii] = ldf(word, (size_t)r * 768 + t + 256 * ii, fF);
  } else {
    int st = ldi(sst, (size_t)b * 8 + j - 1, fI);
    int en = ldi(sen, (size_t)b * 8 + j - 1, fI);
    for (int s = st; s <= en; ++s) {
      int r = ldi(src, (size_t)b * 512 + s, fI);
#pragma unroll
      for (int ii = 0; ii < 3; ++ii) v[ii] += ldf(word, (size_t)r * 768 + t + 256 * ii, fF);
    }
  }
#pragma unroll
  for (int ii = 0; ii < 3; ++ii) x[(size_t)g * 768 + t + 256 * ii] = v[ii];
}

// ---------------------------------------------------------------------------
// k_csr: symmetrized edges + self loops -> CSR by dst. Single block.
// ---------------------------------------------------------------------------
__global__ __launch_bounds__(1024) void k_csr(const void* __restrict__ edge,
                                              const int* __restrict__ flg,
                                              int* __restrict__ csr_off,
                                              int* __restrict__ csr_src) {
  int fI = flg[1];
  __shared__ int cnt[576];
  __shared__ int off[577];
  __shared__ int fill[576];
  int t = threadIdx.x;
  for (int i = t; i < 576; i += 1024) cnt[i] = 0;
  __syncthreads();
  for (int e = t; e < 8768; e += 1024) {
    int di;
    if (e < 4096) di = ldi(edge, (size_t)4096 + e, fI);
    else if (e < 8192) di = ldi(edge, (size_t)e - 4096, fI);
    else di = e - 8192;
    atomicAdd(&cnt[di], 1);
  }
  __syncthreads();
  if (t == 0) {
    int a = 0;
    for (int i = 0; i < 576; ++i) { off[i] = a; a += cnt[i]; }
    off[576] = a;
  }
  __syncthreads();
  for (int i = t; i < 577; i += 1024) csr_off[i] = off[i];
  for (int i = t; i < 576; i += 1024) fill[i] = off[i];
  __syncthreads();
  for (int e = t; e < 8768; e += 1024) {
    int si, di;
    if (e < 4096)      { si = ldi(edge, (size_t)e, fI); di = ldi(edge, (size_t)4096 + e, fI); }
    else if (e < 8192) { si = ldi(edge, (size_t)e, fI); di = ldi(edge, (size_t)e - 4096, fI); }
    else               { si = e - 8192;                 di = si; }
    int pos = atomicAdd(&fill[di], 1);
    csr_src[pos] = si;
  }
}

// ---------------------------------------------------------------------------
// k_gemm: C[m][n] = sum_k x[m][k]*W[layer][k][n] for n<768; folded alpha
// cols (F) for 768..775; 0 for 776..831. Block = 4 rows x 256 cols; x rows
// staged in LDS; W reads coalesced across n. Grid (4, 144). Layer offset in
// elements computed in-kernel.
// ---------------------------------------------------------------------------
__global__ __launch_bounds__(256) void k_gemm(const float* __restrict__ x,
                                              const void* __restrict__ Wg,
                                              const float* __restrict__ F,
                                              const int* __restrict__ flg,
                                              int layer,
                                              float* __restrict__ C) {
  int fF = flg[0];
  __shared__ float xs[4][768];
  int t = threadIdx.x;
  int m0 = blockIdx.y * 4;
  for (int i = t; i < 3072; i += 256) {
    int rr = i / 768, cc = i - rr * 768;
    xs[rr][cc] = x[(size_t)(m0 + rr) * 768 + cc];
  }
  __syncthreads();
  int n = blockIdx.x * 256 + t;
  if (n >= 832) return;
  float acc[4] = {0.f, 0.f, 0.f, 0.f};
  size_t wbase = (size_t)layer * 768 * 768;
  if (n < 768) {
    if (fF) {
      const float* Wf = (const float*)Wg + wbase;
      for (int k = 0; k < 768; ++k) {
        float wv = Wf[(size_t)k * 768 + n];
#pragma unroll
        for (int r = 0; r < 4; ++r) acc[r] += xs[r][k] * wv;
      }
    } else {
      const unsigned short* Wb = (const unsigned short*)Wg + wbase;
      for (int k = 0; k < 768; ++k) {
        float wv = b2f(Wb[(size_t)k * 768 + n]);
#pragma unroll
        for (int r = 0; r < 4; ++r) acc[r] += xs[r][k] * wv;
      }
    }
  } else if (n < 776) {
    const float* f = F + (size_t)(n - 768) * 768;
    for (int k = 0; k < 768; ++k) {
      float wv = f[k];
#pragma unroll
      for (int r = 0; r < 4; ++r) acc[r] += xs[r][k] * wv;
    }
  }
#pragma unroll
  for (int r = 0; r < 4; ++r) C[(size_t)(m0 + r) * 832 + n] = acc[r];
}

// ---------------------------------------------------------------------------
// k_gat: one thread per (node, feature). Per-thread edge loop recomputes exp
// weights (redundant across a head's 192 threads but race-free). Logit
// clamped to [-60,40] -> always finite. Softmax shift skipped (logits O(5));
// denominator applied after aggregation (linear). Overwrites x in place
// (reads only C). den >= exp(-60) > 0 via the self-loop.
// ---------------------------------------------------------------------------
__global__ __launch_bounds__(256) void k_gat(const float* __restrict__ C,
                                             const int* __restrict__ off,
                                             const int* __restrict__ srcs,
                                             const void* __restrict__ bG,
                                             const int* __restrict__ flg,
                                             int layer,
                                             float* __restrict__ x) {
  int fF = flg[0];
  int idx = blockIdx.x * 256 + threadIdx.x;  // 576*768
  int n = idx / 768, d = idx - n * 768, h = d / 192;
  float aDv = C[(size_t)n * 832 + 772 + h];
  int e0 = off[n], e1 = off[n + 1];
  float num = 0.f, den = 0.f;
  for (int e = e0; e < e1; ++e) {
    int s = srcs[e];
    float lg = C[(size_t)s * 832 + 768 + h] + aDv;
    float lrel = lg < 0.f ? 0.2f * lg : lg;
    lrel = fminf(fmaxf(lrel, -60.f), 40.f);
    float w = __expf(lrel);
    num += w * C[(size_t)s * 832 + d];
    den += w;
  }
  float g = gelu_exact(num / den + ldf(bG, (size_t)layer * 768 + d, fF));
  x[(size_t)n * 768 + d] = g;
}

// ---------------------------------------------------------------------------
// k_final: emb = (CLS? gnn_x : word[src]) + pos[s] + seg + type; LayerNorm;
// dual-dtype out. One row per 128-thread block, 6 features/thread.
// ---------------------------------------------------------------------------
__global__ __launch_bounds__(128) void k_final(const void* __restrict__ src,
                                               const void* __restrict__ seg,
                                               const void* __restrict__ typ,
                                               const void* __restrict__ word,
                                               const void* __restrict__ post,
                                               const void* __restrict__ segt,
                                               const void* __restrict__ typt,
                                               const void* __restrict__ gamma,
                                               const void* __restrict__ beta,
                                               const float* __restrict__ x,
                                               const int* __restrict__ flg,
                                               void* __restrict__ out) {
  int fF = flg[0], fI = flg[1];
  int r = blockIdx.x, t = threadIdx.x;
  int b = r >> 9, s = r & 511;
  int sg = ldi(seg, (size_t)r, fI), tp = ldi(typ, (size_t)r, fI);
  int wrow = ldi(src, (size_t)r, fI);
  const float* xr = x + (size_t)b * 9 * 768;
  bool cls = (s == 0);
  float v[6];
  float sum = 0.f, sq = 0.f;
#pragma unroll
  for (int i = 0; i < 6; ++i) {
    int d = t + 128 * i;
    float xv = cls ? xr[d] : ldf(word, (size_t)wrow * 768 + d, fF);
    xv += ldf(post, (size_t)s * 768 + d, fF);
    xv += ldf(segt, (size_t)sg * 768 + d, fF);
    xv += ldf(typt, (size_t)tp * 768 + d, fF);
    v[i] = xv;
    sum += xv; sq += xv * xv;
  }
#pragma unroll
  for (int o = 32; o > 0; o >>= 1) { sum += __shfl_down(sum, o); sq += __shfl_down(sq, o); }
  __shared__ float rs[2][2];
  int w = t >> 6;
  if ((t & 63) == 0) { rs[w][0] = sum; rs[w][1] = sq; }
  __syncthreads();
  sum = rs[0][0] + rs[1][0]; sq = rs[0][1] + rs[1][1];
  float mu = sum * (1.f / 768.f);
  float var = fmaxf(sq * (1.f / 768.f) - mu * mu, 0.f);
  float rstd = rsqrtf(var + 1e-6f);
#pragma unroll
  for (int i = 0; i < 6; ++i) {
    int d = t + 128 * i;
    float y = ldf(gamma, (size_t)d, fF) * (v[i] - mu) * rstd + ldf(beta, (size_t)d, fF);
    if (fF) ((float*)out)[(size_t)r * 768 + d] = y;
    else ((unsigned short*)out)[(size_t)r * 768 + d] = f2b(y);
  }
}

extern "C" void kernel_launch(void* const* d_in, const int* in_sizes, int n_in,
                              void* d_out, int out_size, void* d_ws, size_t ws_size,
                              hipStream_t stream) {
  const void* src  = d_in[0];
  const void* seg  = d_in[1];
  const void* typ  = d_in[2];
  const void* pos  = d_in[3];
  const void* sst  = d_in[4];
  const void* sen  = d_in[5];
  const void* edge = d_in[6];
  const void* word = d_in[7];
  const void* post = d_in[8];
  const void* segt = d_in[9];
  const void* typt = d_in[10];
  const void* gamma = d_in[11];
  const void* beta  = d_in[12];
  const void* Wg    = d_in[13];
  const void* aS    = d_in[14];
  const void* aD    = d_in[15];
  const void* bG    = d_in[16];

  char* ws = (char*)d_ws;
  float* x  = (float*)(ws);                 // 576*768*4 = 1,769,472
  float* C  = (float*)(ws + 1769472);       // 576*832*4 = 1,916,928
  float* F  = (float*)(ws + 3686400);       // 5*8*768*4 =   122,880
  int* csr_off = (int*)(ws + 3809280);      // 577*4 (pad to 2,320)
  int* csr_src = (int*)(ws + 3811600);      // 8768*4 = 35,072
  int* flags   = (int*)(ws + 3846672);      // 2*4

  k_detect<<<dim3(1), dim3(64), 0, stream>>>((const unsigned short*)word, (const int*)pos, flags);
  k_fold<<<dim3(15), dim3(256), 0, stream>>>(Wg, aS, aD, flags, F);
  k_nodes<<<dim3(576), dim3(256), 0, stream>>>(src, sst, sen, word, flags, x);
  k_csr<<<dim3(1), dim3(1024), 0, stream>>>(edge, flags, csr_off, csr_src);
  for (int l = 0; l < 5; ++l) {
    k_gemm<<<dim3(4, 144), dim3(256), 0, stream>>>(x, Wg, F + (size_t)l * 8 * 768, flags, l, C);
    k_gat<<<dim3(1728), dim3(256), 0, stream>>>(C, csr_off, csr_src, bG, flags, l, x);
  }
  k_final<<<dim3(32768), dim3(128), 0, stream>>>(src, seg, typ, word, post, segt, typt,
                                                 gamma, beta, x, flags, d_out);
}

// Round 5
// 563.624 us; speedup vs baseline: 1.1944x; 1.1944x over previous
//
#include <hip/hip_runtime.h>

// BertEmbedding + 5-layer GAT on MI355X (gfx950). Round 5: k_fold rewritten
// wave-per-row (was 107 us, 0.66% occupancy, serial uncoalesced chain);
// k_detect parallelized across one wave. All else identical to the passing
// round-4 kernel. Floats confirmed f32 via round-4 evidence; detector kept.
// Workspace ~3.9 MB.

#define DEV __device__ __forceinline__

DEV float b2f(unsigned int u) { union { unsigned int i; float f; } v; v.i = u << 16; return v.f; }
DEV unsigned short f2b(float f) {
  union { float f; unsigned int i; } v; v.f = f;
  return (unsigned short)((v.i + 0x7fffu + ((v.i >> 16) & 1u)) >> 16);
}
DEV float gelu_exact(float x) { return 0.5f * x * (1.f + erff(x * 0.70710678118654752f)); }

// dual-dtype loads. fF: floats are f32 (else bf16). fI: ints are int64
// (little-endian low word; all values small non-negative) else int32.
DEV float ldf(const void* p, size_t i, int fF) {
  return fF ? ((const float*)p)[i] : b2f(((const unsigned short*)p)[i]);
}
DEV int ldi(const void* p, size_t i, int fI) {
  return fI ? ((const int*)p)[2 * i] : ((const int*)p)[i];
}

// ---------------------------------------------------------------------------
// k_detect: flags[0]=1 iff float tables are f32; flags[1]=1 iff ints are
// int64. One wave, 8 elements/lane, shuffle-reduced.
// ---------------------------------------------------------------------------
__global__ __launch_bounds__(64) void k_detect(const unsigned short* __restrict__ word,
                                               const int* __restrict__ pos,
                                               int* __restrict__ flags) {
  int t = threadIdx.x;
  int crazy = 0;
  for (int i = t; i < 512; i += 64) {
    unsigned int e = (word[i] >> 7) & 0xffu;  // bf16 exponent field
    if (e >= 135u || (e >= 1u && e <= 100u)) crazy++;
  }
#pragma unroll
  for (int o = 32; o > 0; o >>= 1) crazy += __shfl_down(crazy, o);
  if (t == 0) {
    flags[0] = (crazy >= 8) ? 1 : 0;
    flags[1] = (pos[1] == 0) ? 1 : 0;
  }
}

// ---------------------------------------------------------------------------
// k_fold: F[l][j][k] (f32) = folded attention columns.
//   j 0..3: sum_d W[l][k][j*192+d]*a_src[l][j][d];  j 4..7: same with a_dst.
// Wave-per-(l,k)-row: lane covers d = lane + 64*i, i = 0..11; head = i/3
// exactly (192 = 3*64). aS/aD staged in LDS (block never spans layers:
// 768 % 4 == 0). W read coalesced once. 960 blocks x 4 waves.
// ---------------------------------------------------------------------------
__global__ __launch_bounds__(256) void k_fold(const void* __restrict__ Wg,
                                              const void* __restrict__ aS,
                                              const void* __restrict__ aD,
                                              const int* __restrict__ flg,
                                              float* __restrict__ F) {
  int fF = flg[0];
  __shared__ float sA[768], sD[768];
  int t = threadIdx.x;
  int R0 = blockIdx.x * 4;            // first row of this block
  int l = R0 / 768;                   // all 4 rows in same layer
  for (int i = t; i < 768; i += 256) {
    sA[i] = ldf(aS, (size_t)l * 768 + i, fF);
    sD[i] = ldf(aD, (size_t)l * 768 + i, fF);
  }
  __syncthreads();
  int wave = t >> 6, lane = t & 63;
  int k = (R0 + wave) - l * 768;
  size_t wbase = ((size_t)l * 768 + k) * 768;
  float accS[4] = {0.f, 0.f, 0.f, 0.f}, accD[4] = {0.f, 0.f, 0.f, 0.f};
#pragma unroll
  for (int i = 0; i < 12; ++i) {
    int d = lane + 64 * i;
    float w = ldf(Wg, wbase + d, fF);
    accS[i / 3] += w * sA[d];
    accD[i / 3] += w * sD[d];
  }
  float* Fl = F + (size_t)l * 8 * 768;
#pragma unroll
  for (int h = 0; h < 4; ++h) {
    float sS = accS[h], sDv = accD[h];
#pragma unroll
    for (int o = 32; o > 0; o >>= 1) {
      sS += __shfl_down(sS, o);
      sDv += __shfl_down(sDv, o);
    }
    if (lane == 0) {
      Fl[(size_t)h * 768 + k] = sS;
      Fl[(size_t)(4 + h) * 768 + k] = sDv;
    }
  }
}

// ---------------------------------------------------------------------------
// k_nodes: node 0 of each example = CLS word emb; nodes 1..8 = inclusive
// span sums. Writes f32 x. 576 blocks x 256 thr, 3 features/thread.
// ---------------------------------------------------------------------------
__global__ __launch_bounds__(256) void k_nodes(const void* __restrict__ src,
                                               const void* __restrict__ sst,
                                               const void* __restrict__ sen,
                                               const void* __restrict__ word,
                                               const int* __restrict__ flg,
                                               float* __restrict__ x) {
  int fF = flg[0], fI = flg[1];
  int g = blockIdx.x, t = threadIdx.x;
  int b = g / 9, j = g % 9;
  float v[3] = {0.f, 0.f, 0.f};
  if (j == 0) {
    int r = ldi(src, (size_t)b * 512, fI);
#pragma unroll
    for (int ii = 0; ii < 3; ++ii) v[ii] = ldf(word, (size_t)r * 768 + t + 256 * ii, fF);
  } else {
    int st = ldi(sst, (size_t)b * 8 + j - 1, fI);
    int en = ldi(sen, (size_t)b * 8 + j - 1, fI);
    for (int s = st; s <= en; ++s) {
      int r = ldi(src, (size_t)b * 512 + s, fI);
#pragma unroll
      for (int ii = 0; ii < 3; ++ii) v[ii] += ldf(word, (size_t)r * 768 + t + 256 * ii, fF);
    }
  }
#pragma unroll
  for (int ii = 0; ii < 3; ++ii) x[(size_t)g * 768 + t + 256 * ii] = v[ii];
}

// ---------------------------------------------------------------------------
// k_csr: symmetrized edges + self loops -> CSR by dst. Single block.
// ---------------------------------------------------------------------------
__global__ __launch_bounds__(1024) void k_csr(const void* __restrict__ edge,
                                              const int* __restrict__ flg,
                                              int* __restrict__ csr_off,
                                              int* __restrict__ csr_src) {
  int fI = flg[1];
  __shared__ int cnt[576];
  __shared__ int off[577];
  __shared__ int fill[576];
  int t = threadIdx.x;
  for (int i = t; i < 576; i += 1024) cnt[i] = 0;
  __syncthreads();
  for (int e = t; e < 8768; e += 1024) {
    int di;
    if (e < 4096) di = ldi(edge, (size_t)4096 + e, fI);
    else if (e < 8192) di = ldi(edge, (size_t)e - 4096, fI);
    else di = e - 8192;
    atomicAdd(&cnt[di], 1);
  }
  __syncthreads();
  if (t == 0) {
    int a = 0;
    for (int i = 0; i < 576; ++i) { off[i] = a; a += cnt[i]; }
    off[576] = a;
  }
  __syncthreads();
  for (int i = t; i < 577; i += 1024) csr_off[i] = off[i];
  for (int i = t; i < 576; i += 1024) fill[i] = off[i];
  __syncthreads();
  for (int e = t; e < 8768; e += 1024) {
    int si, di;
    if (e < 4096)      { si = ldi(edge, (size_t)e, fI); di = ldi(edge, (size_t)4096 + e, fI); }
    else if (e < 8192) { si = ldi(edge, (size_t)e, fI); di = ldi(edge, (size_t)e - 4096, fI); }
    else               { si = e - 8192;                 di = si; }
    int pos = atomicAdd(&fill[di], 1);
    csr_src[pos] = si;
  }
}

// ---------------------------------------------------------------------------
// k_gemm: C[m][n] = sum_k x[m][k]*W[layer][k][n] for n<768; folded alpha
// cols (F) for 768..775; 0 for 776..831. Block = 4 rows x 256 cols; x rows
// staged in LDS; W reads coalesced across n. Grid (4, 144). Layer offset in
// elements computed in-kernel.
// ---------------------------------------------------------------------------
__global__ __launch_bounds__(256) void k_gemm(const float* __restrict__ x,
                                              const void* __restrict__ Wg,
                                              const float* __restrict__ F,
                                              const int* __restrict__ flg,
                                              int layer,
                                              float* __restrict__ C) {
  int fF = flg[0];
  __shared__ float xs[4][768];
  int t = threadIdx.x;
  int m0 = blockIdx.y * 4;
  for (int i = t; i < 3072; i += 256) {
    int rr = i / 768, cc = i - rr * 768;
    xs[rr][cc] = x[(size_t)(m0 + rr) * 768 + cc];
  }
  __syncthreads();
  int n = blockIdx.x * 256 + t;
  if (n >= 832) return;
  float acc[4] = {0.f, 0.f, 0.f, 0.f};
  size_t wbase = (size_t)layer * 768 * 768;
  if (n < 768) {
    if (fF) {
      const float* Wf = (const float*)Wg + wbase;
      for (int k = 0; k < 768; ++k) {
        float wv = Wf[(size_t)k * 768 + n];
#pragma unroll
        for (int r = 0; r < 4; ++r) acc[r] += xs[r][k] * wv;
      }
    } else {
      const unsigned short* Wb = (const unsigned short*)Wg + wbase;
      for (int k = 0; k < 768; ++k) {
        float wv = b2f(Wb[(size_t)k * 768 + n]);
#pragma unroll
        for (int r = 0; r < 4; ++r) acc[r] += xs[r][k] * wv;
      }
    }
  } else if (n < 776) {
    const float* f = F + (size_t)(n - 768) * 768;
    for (int k = 0; k < 768; ++k) {
      float wv = f[k];
#pragma unroll
      for (int r = 0; r < 4; ++r) acc[r] += xs[r][k] * wv;
    }
  }
#pragma unroll
  for (int r = 0; r < 4; ++r) C[(size_t)(m0 + r) * 832 + n] = acc[r];
}

// ---------------------------------------------------------------------------
// k_gat: one thread per (node, feature). Per-thread edge loop recomputes exp
// weights (redundant across a head's 192 threads but race-free). Logit
// clamped to [-60,40] -> always finite. Softmax shift skipped (logits O(5));
// denominator applied after aggregation (linear). Overwrites x in place
// (reads only C).
// ---------------------------------------------------------------------------
__global__ __launch_bounds__(256) void k_gat(const float* __restrict__ C,
                                             const int* __restrict__ off,
                                             const int* __restrict__ srcs,
                                             const void* __restrict__ bG,
                                             const int* __restrict__ flg,
                                             int layer,
                                             float* __restrict__ x) {
  int fF = flg[0];
  int idx = blockIdx.x * 256 + threadIdx.x;  // 576*768
  int n = idx / 768, d = idx - n * 768, h = d / 192;
  float aDv = C[(size_t)n * 832 + 772 + h];
  int e0 = off[n], e1 = off[n + 1];
  float num = 0.f, den = 0.f;
  for (int e = e0; e < e1; ++e) {
    int s = srcs[e];
    float lg = C[(size_t)s * 832 + 768 + h] + aDv;
    float lrel = lg < 0.f ? 0.2f * lg : lg;
    lrel = fminf(fmaxf(lrel, -60.f), 40.f);
    float w = __expf(lrel);
    num += w * C[(size_t)s * 832 + d];
    den += w;
  }
  float g = gelu_exact(num / den + ldf(bG, (size_t)layer * 768 + d, fF));
  x[(size_t)n * 768 + d] = g;
}

// ---------------------------------------------------------------------------
// k_final: emb = (CLS? gnn_x : word[src]) + pos[s] + seg + type; LayerNorm;
// dual-dtype out. One row per 128-thread block, 6 features/thread.
// ---------------------------------------------------------------------------
__global__ __launch_bounds__(128) void k_final(const void* __restrict__ src,
                                               const void* __restrict__ seg,
                                               const void* __restrict__ typ,
                                               const void* __restrict__ word,
                                               const void* __restrict__ post,
                                               const void* __restrict__ segt,
                                               const void* __restrict__ typt,
                                               const void* __restrict__ gamma,
                                               const void* __restrict__ beta,
                                               const float* __restrict__ x,
                                               const int* __restrict__ flg,
                                               void* __restrict__ out) {
  int fF = flg[0], fI = flg[1];
  int r = blockIdx.x, t = threadIdx.x;
  int b = r >> 9, s = r & 511;
  int sg = ldi(seg, (size_t)r, fI), tp = ldi(typ, (size_t)r, fI);
  int wrow = ldi(src, (size_t)r, fI);
  const float* xr = x + (size_t)b * 9 * 768;
  bool cls = (s == 0);
  float v[6];
  float sum = 0.f, sq = 0.f;
#pragma unroll
  for (int i = 0; i < 6; ++i) {
    int d = t + 128 * i;
    float xv = cls ? xr[d] : ldf(word, (size_t)wrow * 768 + d, fF);
    xv += ldf(post, (size_t)s * 768 + d, fF);
    xv += ldf(segt, (size_t)sg * 768 + d, fF);
    xv += ldf(typt, (size_t)tp * 768 + d, fF);
    v[i] = xv;
    sum += xv; sq += xv * xv;
  }
#pragma unroll
  for (int o = 32; o > 0; o >>= 1) { sum += __shfl_down(sum, o); sq += __shfl_down(sq, o); }
  __shared__ float rs[2][2];
  int w = t >> 6;
  if ((t & 63) == 0) { rs[w][0] = sum; rs[w][1] = sq; }
  __syncthreads();
  sum = rs[0][0] + rs[1][0]; sq = rs[0][1] + rs[1][1];
  float mu = sum * (1.f / 768.f);
  float var = fmaxf(sq * (1.f / 768.f) - mu * mu, 0.f);
  float rstd = rsqrtf(var + 1e-6f);
#pragma unroll
  for (int i = 0; i < 6; ++i) {
    int d = t + 128 * i;
    float y = ldf(gamma, (size_t)d, fF) * (v[i] - mu) * rstd + ldf(beta, (size_t)d, fF);
    if (fF) ((float*)out)[(size_t)r * 768 + d] = y;
    else ((unsigned short*)out)[(size_t)r * 768 + d] = f2b(y);
  }
}

extern "C" void kernel_launch(void* const* d_in, const int* in_sizes, int n_in,
                              void* d_out, int out_size, void* d_ws, size_t ws_size,
                              hipStream_t stream) {
  const void* src  = d_in[0];
  const void* seg  = d_in[1];
  const void* typ  = d_in[2];
  const void* pos  = d_in[3];
  const void* sst  = d_in[4];
  const void* sen  = d_in[5];
  const void* edge = d_in[6];
  const void* word = d_in[7];
  const void* post = d_in[8];
  const void* segt = d_in[9];
  const void* typt = d_in[10];
  const void* gamma = d_in[11];
  const void* beta  = d_in[12];
  const void* Wg    = d_in[13];
  const void* aS    = d_in[14];
  const void* aD    = d_in[15];
  const void* bG    = d_in[16];

  char* ws = (char*)d_ws;
  float* x  = (float*)(ws);                 // 576*768*4 = 1,769,472
  float* C  = (float*)(ws + 1769472);       // 576*832*4 = 1,916,928
  float* F  = (float*)(ws + 3686400);       // 5*8*768*4 =   122,880
  int* csr_off = (int*)(ws + 3809280);      // 577*4 (pad to 2,320)
  int* csr_src = (int*)(ws + 3811600);      // 8768*4 = 35,072
  int* flags   = (int*)(ws + 3846672);      // 2*4

  k_detect<<<dim3(1), dim3(64), 0, stream>>>((const unsigned short*)word, (const int*)pos, flags);
  k_fold<<<dim3(960), dim3(256), 0, stream>>>(Wg, aS, aD, flags, F);
  k_nodes<<<dim3(576), dim3(256), 0, stream>>>(src, sst, sen, word, flags, x);
  k_csr<<<dim3(1), dim3(1024), 0, stream>>>(edge, flags, csr_off, csr_src);
  for (int l = 0; l < 5; ++l) {
    k_gemm<<<dim3(4, 144), dim3(256), 0, stream>>>(x, Wg, F + (size_t)l * 8 * 768, flags, l, C);
    k_gat<<<dim3(1728), dim3(256), 0, stream>>>(C, csr_off, csr_src, bG, flags, l, x);
  }
  k_final<<<dim3(32768), dim3(128), 0, stream>>>(src, seg, typ, word, post, segt, typt,
                                                 gamma, beta, x, flags, d_out);
}

// Round 6
// 515.202 us; speedup vs baseline: 1.3066x; 1.0940x over previous
//
#include <hip/hip_runtime.h>

// BertEmbedding + 5-layer GAT on MI355X (gfx950). Round 6:
//  - k_gemm -> MFMA bf16 with split-hi/lo emulation (~f32 accuracy):
//    x=xh+xl, W=Wh+Wl, acc = xh*Wh + xh*Wl + xl*Wh. Old VALU GEMM was
//    LDS-issue-bound (~67 us/layer: 4 ds_read_b32 per k-iter).
//  - k_prep (new, per layer): W[k][n] f32 -> Bh/Bl bf16 [n][k] (transposed)
//    with folded alpha cols (from F) as rows 768..775, zeros to 831.
//  - k_final: wave-per-row float4 (was 74 us @ 2.1 TB/s scalar).
//  - dtype detector kept (f32 confirmed by round-4/5 counters).
// Workspace ~8.2 MB.

#define DEV __device__ __forceinline__

typedef short s16x8 __attribute__((ext_vector_type(8)));
typedef float f32x4 __attribute__((ext_vector_type(4)));

DEV float b2f(unsigned int u) { union { unsigned int i; float f; } v; v.i = u << 16; return v.f; }
DEV unsigned short f2b(float f) {
  union { float f; unsigned int i; } v; v.f = f;
  return (unsigned short)((v.i + 0x7fffu + ((v.i >> 16) & 1u)) >> 16);
}
DEV float gelu_exact(float x) { return 0.5f * x * (1.f + erff(x * 0.70710678118654752f)); }

// dual-dtype loads. fF: floats are f32 (else bf16). fI: ints are int64.
DEV float ldf(const void* p, size_t i, int fF) {
  return fF ? ((const float*)p)[i] : b2f(((const unsigned short*)p)[i]);
}
DEV int ldi(const void* p, size_t i, int fI) {
  return fI ? ((const int*)p)[2 * i] : ((const int*)p)[i];
}

// ---------------------------------------------------------------------------
// k_detect: flags[0]=1 iff float tables are f32; flags[1]=1 iff ints int64.
// ---------------------------------------------------------------------------
__global__ __launch_bounds__(64) void k_detect(const unsigned short* __restrict__ word,
                                               const int* __restrict__ pos,
                                               int* __restrict__ flags) {
  int t = threadIdx.x;
  int crazy = 0;
  for (int i = t; i < 512; i += 64) {
    unsigned int e = (word[i] >> 7) & 0xffu;
    if (e >= 135u || (e >= 1u && e <= 100u)) crazy++;
  }
#pragma unroll
  for (int o = 32; o > 0; o >>= 1) crazy += __shfl_down(crazy, o);
  if (t == 0) {
    flags[0] = (crazy >= 8) ? 1 : 0;
    flags[1] = (pos[1] == 0) ? 1 : 0;
  }
}

// ---------------------------------------------------------------------------
// k_fold: F[l][j][k] (f32) folded attention columns (j 0..3 a_src, 4..7
// a_dst). Wave-per-(l,k)-row, coalesced, shuffle-reduced. 960 blocks.
// ---------------------------------------------------------------------------
__global__ __launch_bounds__(256) void k_fold(const void* __restrict__ Wg,
                                              const void* __restrict__ aS,
                                              const void* __restrict__ aD,
                                              const int* __restrict__ flg,
                                              float* __restrict__ F) {
  int fF = flg[0];
  __shared__ float sA[768], sD[768];
  int t = threadIdx.x;
  int R0 = blockIdx.x * 4;
  int l = R0 / 768;
  for (int i = t; i < 768; i += 256) {
    sA[i] = ldf(aS, (size_t)l * 768 + i, fF);
    sD[i] = ldf(aD, (size_t)l * 768 + i, fF);
  }
  __syncthreads();
  int wave = t >> 6, lane = t & 63;
  int k = (R0 + wave) - l * 768;
  size_t wbase = ((size_t)l * 768 + k) * 768;
  float accS[4] = {0.f, 0.f, 0.f, 0.f}, accD[4] = {0.f, 0.f, 0.f, 0.f};
#pragma unroll
  for (int i = 0; i < 12; ++i) {
    int d = lane + 64 * i;
    float w = ldf(Wg, wbase + d, fF);
    accS[i / 3] += w * sA[d];
    accD[i / 3] += w * sD[d];
  }
  float* Fl = F + (size_t)l * 8 * 768;
#pragma unroll
  for (int h = 0; h < 4; ++h) {
    float sS = accS[h], sDv = accD[h];
#pragma unroll
    for (int o = 32; o > 0; o >>= 1) {
      sS += __shfl_down(sS, o);
      sDv += __shfl_down(sDv, o);
    }
    if (lane == 0) {
      Fl[(size_t)h * 768 + k] = sS;
      Fl[(size_t)(4 + h) * 768 + k] = sDv;
    }
  }
}

// ---------------------------------------------------------------------------
// k_prep: one GAT layer's B matrix for MFMA: Bh/Bl bf16, layout [n 832][k
// 768]. n<768: W[l][k][n] split hi/lo; n in 768..775: F[l][n-768][k];
// n>=776: 0. 64x64 tiles via LDS transpose. 156 blocks (12 kt x 13 nt).
// ---------------------------------------------------------------------------
__global__ __launch_bounds__(256) void k_prep(const void* __restrict__ Wg,
                                              const float* __restrict__ F,
                                              const int* __restrict__ flg,
                                              int layer,
                                              unsigned short* __restrict__ Bh,
                                              unsigned short* __restrict__ Bl) {
  int fF = flg[0];
  __shared__ float tile[64][65];
  int bid = blockIdx.x, t = threadIdx.x;
  int kt = bid / 13, nt = bid % 13;
  int k0 = kt * 64, n0 = nt * 64;
#pragma unroll
  for (int i = 0; i < 16; ++i) {
    int e = t + 256 * i, rk = e >> 6, cn = e & 63;
    float v;
    if (nt < 12) {
      v = ldf(Wg, ((size_t)layer * 768 + k0 + rk) * 768 + n0 + cn, fF);
    } else {
      v = (cn < 8) ? F[(size_t)layer * 8 * 768 + (size_t)cn * 768 + k0 + rk] : 0.f;
    }
    tile[rk][cn] = v;
  }
  __syncthreads();
#pragma unroll
  for (int i = 0; i < 16; ++i) {
    int e = t + 256 * i, rn = e >> 6, ck = e & 63;
    float v = tile[ck][rn];
    unsigned short hi = f2b(v);
    float lo = v - b2f((unsigned int)hi);
    size_t o = (size_t)(n0 + rn) * 768 + k0 + ck;
    Bh[o] = hi;
    Bl[o] = f2b(lo);
  }
}

// ---------------------------------------------------------------------------
// k_nodes: node 0 = CLS word emb; nodes 1..8 = inclusive span sums. Writes
// split-bf16 xh/xl (GEMM A input). 576 blocks x 256 thr.
// ---------------------------------------------------------------------------
__global__ __launch_bounds__(256) void k_nodes(const void* __restrict__ src,
                                               const void* __restrict__ sst,
                                               const void* __restrict__ sen,
                                               const void* __restrict__ word,
                                               const int* __restrict__ flg,
                                               unsigned short* __restrict__ xh,
                                               unsigned short* __restrict__ xl) {
  int fF = flg[0], fI = flg[1];
  int g = blockIdx.x, t = threadIdx.x;
  int b = g / 9, j = g % 9;
  float v[3] = {0.f, 0.f, 0.f};
  if (j == 0) {
    int r = ldi(src, (size_t)b * 512, fI);
#pragma unroll
    for (int ii = 0; ii < 3; ++ii) v[ii] = ldf(word, (size_t)r * 768 + t + 256 * ii, fF);
  } else {
    int st = ldi(sst, (size_t)b * 8 + j - 1, fI);
    int en = ldi(sen, (size_t)b * 8 + j - 1, fI);
    for (int s = st; s <= en; ++s) {
      int r = ldi(src, (size_t)b * 512 + s, fI);
#pragma unroll
      for (int ii = 0; ii < 3; ++ii) v[ii] += ldf(word, (size_t)r * 768 + t + 256 * ii, fF);
    }
  }
#pragma unroll
  for (int ii = 0; ii < 3; ++ii) {
    float g0 = v[ii];
    unsigned short hi = f2b(g0);
    size_t o = (size_t)g * 768 + t + 256 * ii;
    xh[o] = hi;
    xl[o] = f2b(g0 - b2f((unsigned int)hi));
  }
}

// ---------------------------------------------------------------------------
// k_csr: symmetrized edges + self loops -> CSR by dst. Single block.
// ---------------------------------------------------------------------------
__global__ __launch_bounds__(1024) void k_csr(const void* __restrict__ edge,
                                              const int* __restrict__ flg,
                                              int* __restrict__ csr_off,
                                              int* __restrict__ csr_src) {
  int fI = flg[1];
  __shared__ int cnt[576];
  __shared__ int off[577];
  __shared__ int fill[576];
  int t = threadIdx.x;
  for (int i = t; i < 576; i += 1024) cnt[i] = 0;
  __syncthreads();
  for (int e = t; e < 8768; e += 1024) {
    int di;
    if (e < 4096) di = ldi(edge, (size_t)4096 + e, fI);
    else if (e < 8192) di = ldi(edge, (size_t)e - 4096, fI);
    else di = e - 8192;
    atomicAdd(&cnt[di], 1);
  }
  __syncthreads();
  if (t == 0) {
    int a = 0;
    for (int i = 0; i < 576; ++i) { off[i] = a; a += cnt[i]; }
    off[576] = a;
  }
  __syncthreads();
  for (int i = t; i < 577; i += 1024) csr_off[i] = off[i];
  for (int i = t; i < 576; i += 1024) fill[i] = off[i];
  __syncthreads();
  for (int e = t; e < 8768; e += 1024) {
    int si, di;
    if (e < 4096)      { si = ldi(edge, (size_t)e, fI); di = ldi(edge, (size_t)4096 + e, fI); }
    else if (e < 8192) { si = ldi(edge, (size_t)e, fI); di = ldi(edge, (size_t)e - 4096, fI); }
    else               { si = e - 8192;                 di = si; }
    int pos = atomicAdd(&fill[di], 1);
    csr_src[pos] = si;
  }
}

// ---------------------------------------------------------------------------
// k_gemm: C[576x832] = x[576x768] @ B^T via MFMA 16x16x32 bf16, split
// emulation acc = xh*Bh + xh*Bl + xl*Bh (~f32 accuracy). Block = 64x64 tile,
// 4 waves (wave w -> rows w*16..15, all 64 cols). C/D mapping (verified):
// col = lane&15, row = (lane>>4)*4 + reg. Grid (9, 13).
// ---------------------------------------------------------------------------
__global__ __launch_bounds__(256) void k_gemm(const unsigned short* __restrict__ xh,
                                              const unsigned short* __restrict__ xl,
                                              const unsigned short* __restrict__ Bh,
                                              const unsigned short* __restrict__ Bl,
                                              float* __restrict__ C) {
  __shared__ __align__(16) unsigned short Ah[64][48];
  __shared__ __align__(16) unsigned short Al[64][48];
  __shared__ __align__(16) unsigned short Bhs[64][48];
  __shared__ __align__(16) unsigned short Bls[64][48];
  int t = threadIdx.x;
  int rt = blockIdx.x, ct = blockIdx.y;
  int wave = t >> 6, lane = t & 63, quad = lane >> 4, lr = lane & 15;
  f32x4 acc[4];
#pragma unroll
  for (int c = 0; c < 4; ++c) acc[c] = (f32x4){0.f, 0.f, 0.f, 0.f};
  int sr = t >> 2, sc = t & 3;  // staging row 0..63, 16B chunk 0..3
  const uint4* Agh = (const uint4*)(xh + (size_t)(rt * 64 + sr) * 768);
  const uint4* Agl = (const uint4*)(xl + (size_t)(rt * 64 + sr) * 768);
  const uint4* Bgh = (const uint4*)(Bh + (size_t)(ct * 64 + sr) * 768);
  const uint4* Bgl = (const uint4*)(Bl + (size_t)(ct * 64 + sr) * 768);
  for (int kk = 0; kk < 24; ++kk) {
    *(uint4*)&Ah[sr][sc * 8] = Agh[kk * 4 + sc];
    *(uint4*)&Al[sr][sc * 8] = Agl[kk * 4 + sc];
    *(uint4*)&Bhs[sr][sc * 8] = Bgh[kk * 4 + sc];
    *(uint4*)&Bls[sr][sc * 8] = Bgl[kk * 4 + sc];
    __syncthreads();
    s16x8 ah = *(const s16x8*)&Ah[wave * 16 + lr][quad * 8];
    s16x8 al = *(const s16x8*)&Al[wave * 16 + lr][quad * 8];
#pragma unroll
    for (int c = 0; c < 4; ++c) {
      s16x8 bh = *(const s16x8*)&Bhs[c * 16 + lr][quad * 8];
      s16x8 bl = *(const s16x8*)&Bls[c * 16 + lr][quad * 8];
      acc[c] = __builtin_amdgcn_mfma_f32_16x16x32_bf16(ah, bh, acc[c], 0, 0, 0);
      acc[c] = __builtin_amdgcn_mfma_f32_16x16x32_bf16(ah, bl, acc[c], 0, 0, 0);
      acc[c] = __builtin_amdgcn_mfma_f32_16x16x32_bf16(al, bh, acc[c], 0, 0, 0);
    }
    __syncthreads();
  }
  int row0 = rt * 64 + wave * 16 + quad * 4;
  int col0 = ct * 64 + lr;
#pragma unroll
  for (int c = 0; c < 4; ++c)
#pragma unroll
    for (int r = 0; r < 4; ++r)
      C[(size_t)(row0 + r) * 832 + col0 + c * 16] = acc[c][r];
}

// ---------------------------------------------------------------------------
// k_gat: one thread per (node, feature). Writes xf (f32, for k_final) and
// split-bf16 xh/xl (next layer's GEMM A). Logit clamped -> always finite.
// ---------------------------------------------------------------------------
__global__ __launch_bounds__(256) void k_gat(const float* __restrict__ C,
                                             const int* __restrict__ off,
                                             const int* __restrict__ srcs,
                                             const void* __restrict__ bG,
                                             const int* __restrict__ flg,
                                             int layer,
                                             float* __restrict__ xf,
                                             unsigned short* __restrict__ xh,
                                             unsigned short* __restrict__ xl) {
  int fF = flg[0];
  int idx = blockIdx.x * 256 + threadIdx.x;  // 576*768
  int n = idx / 768, d = idx - n * 768, h = d / 192;
  float aDv = C[(size_t)n * 832 + 772 + h];
  int e0 = off[n], e1 = off[n + 1];
  float num = 0.f, den = 0.f;
  for (int e = e0; e < e1; ++e) {
    int s = srcs[e];
    float lg = C[(size_t)s * 832 + 768 + h] + aDv;
    float lrel = lg < 0.f ? 0.2f * lg : lg;
    lrel = fminf(fmaxf(lrel, -60.f), 40.f);
    float w = __expf(lrel);
    num += w * C[(size_t)s * 832 + d];
    den += w;
  }
  float g = gelu_exact(num / den + ldf(bG, (size_t)layer * 768 + d, fF));
  xf[idx] = g;
  unsigned short hi = f2b(g);
  xh[idx] = hi;
  xl[idx] = f2b(g - b2f((unsigned int)hi));
}

// ---------------------------------------------------------------------------
// k_final: emb = (CLS? gnn_x : word[src]) + pos[s] + seg + type; LayerNorm.
// Wave-per-row, float4 loads/stores on the f32 path (confirmed dtype);
// scalar bf16 fallback kept. Grid 8192 x 256 (4 rows/block).
// ---------------------------------------------------------------------------
__global__ __launch_bounds__(256) void k_final(const void* __restrict__ src,
                                               const void* __restrict__ seg,
                                               const void* __restrict__ typ,
                                               const void* __restrict__ word,
                                               const void* __restrict__ post,
                                               const void* __restrict__ segt,
                                               const void* __restrict__ typt,
                                               const void* __restrict__ gamma,
                                               const void* __restrict__ beta,
                                               const float* __restrict__ xf,
                                               const int* __restrict__ flg,
                                               void* __restrict__ out) {
  int fF = flg[0], fI = flg[1];
  int wave = threadIdx.x >> 6, lane = threadIdx.x & 63;
  int r = blockIdx.x * 4 + wave;
  int b = r >> 9, s = r & 511;
  int sg = ldi(seg, (size_t)r, fI), tp = ldi(typ, (size_t)r, fI);
  int wrow = ldi(src, (size_t)r, fI);
  bool cls = (s == 0);
  float sum = 0.f, sq = 0.f;
  f32x4 vv[3];
  float vs[12];
  if (fF) {
    const f32x4* wr = (const f32x4*)((const float*)word + (size_t)wrow * 768);
    const f32x4* pr = (const f32x4*)((const float*)post + (size_t)s * 768);
    const f32x4* sr = (const f32x4*)((const float*)segt + (size_t)sg * 768);
    const f32x4* tr = (const f32x4*)((const float*)typt + (size_t)tp * 768);
    const f32x4* xr = (const f32x4*)(xf + (size_t)b * 9 * 768);
#pragma unroll
    for (int j = 0; j < 3; ++j) {
      int p = lane + 64 * j;
      f32x4 a = cls ? xr[p] : wr[p];
      a += pr[p]; a += sr[p]; a += tr[p];
      vv[j] = a;
#pragma unroll
      for (int c = 0; c < 4; ++c) { sum += a[c]; sq += a[c] * a[c]; }
    }
  } else {
#pragma unroll
    for (int j = 0; j < 12; ++j) {
      int d = lane + 64 * j;
      float xv = cls ? xf[(size_t)b * 9 * 768 + d] : ldf(word, (size_t)wrow * 768 + d, fF);
      xv += ldf(post, (size_t)s * 768 + d, fF);
      xv += ldf(segt, (size_t)sg * 768 + d, fF);
      xv += ldf(typt, (size_t)tp * 768 + d, fF);
      vs[j] = xv;
      sum += xv; sq += xv * xv;
    }
  }
#pragma unroll
  for (int o = 32; o > 0; o >>= 1) { sum += __shfl_down(sum, o); sq += __shfl_down(sq, o); }
  sum = __shfl(sum, 0); sq = __shfl(sq, 0);
  float mu = sum * (1.f / 768.f);
  float var = fmaxf(sq * (1.f / 768.f) - mu * mu, 0.f);
  float rstd = rsqrtf(var + 1e-6f);
  if (fF) {
    const f32x4* gm = (const f32x4*)gamma;
    const f32x4* bt = (const f32x4*)beta;
    f32x4* orow = (f32x4*)((float*)out + (size_t)r * 768);
#pragma unroll
    for (int j = 0; j < 3; ++j) {
      int p = lane + 64 * j;
      f32x4 g4 = gm[p], b4 = bt[p], y;
#pragma unroll
      for (int c = 0; c < 4; ++c) y[c] = g4[c] * (vv[j][c] - mu) * rstd + b4[c];
      orow[p] = y;
    }
  } else {
#pragma unroll
    for (int j = 0; j < 12; ++j) {
      int d = lane + 64 * j;
      float y = ldf(gamma, (size_t)d, fF) * (vs[j] - mu) * rstd + ldf(beta, (size_t)d, fF);
      ((unsigned short*)out)[(size_t)r * 768 + d] = f2b(y);
    }
  }
}

extern "C" void kernel_launch(void* const* d_in, const int* in_sizes, int n_in,
                              void* d_out, int out_size, void* d_ws, size_t ws_size,
                              hipStream_t stream) {
  const void* src  = d_in[0];
  const void* seg  = d_in[1];
  const void* typ  = d_in[2];
  const void* pos  = d_in[3];
  const void* sst  = d_in[4];
  const void* sen  = d_in[5];
  const void* edge = d_in[6];
  const void* word = d_in[7];
  const void* post = d_in[8];
  const void* segt = d_in[9];
  const void* typt = d_in[10];
  const void* gamma = d_in[11];
  const void* beta  = d_in[12];
  const void* Wg    = d_in[13];
  const void* aS    = d_in[14];
  const void* aD    = d_in[15];
  const void* bG    = d_in[16];

  char* ws = (char*)d_ws;
  float* xf = (float*)(ws);                              // 1,769,472
  float* C  = (float*)(ws + 1769472);                    // 1,916,928
  unsigned short* xh = (unsigned short*)(ws + 3686400);  //   884,736
  unsigned short* xl = (unsigned short*)(ws + 4571136);  //   884,736
  unsigned short* Bh = (unsigned short*)(ws + 5455872);  // 1,277,952
  unsigned short* Bl = (unsigned short*)(ws + 6733824);  // 1,277,952
  float* F = (float*)(ws + 8011776);                     //   122,880
  int* csr_off = (int*)(ws + 8134656);                   //     2,320 (pad)
  int* csr_src = (int*)(ws + 8136976);                   //    35,072
  int* flags   = (int*)(ws + 8172048);                   //         8

  k_detect<<<dim3(1), dim3(64), 0, stream>>>((const unsigned short*)word, (const int*)pos, flags);
  k_fold<<<dim3(960), dim3(256), 0, stream>>>(Wg, aS, aD, flags, F);
  k_nodes<<<dim3(576), dim3(256), 0, stream>>>(src, sst, sen, word, flags, xh, xl);
  k_csr<<<dim3(1), dim3(1024), 0, stream>>>(edge, flags, csr_off, csr_src);
  for (int l = 0; l < 5; ++l) {
    k_prep<<<dim3(156), dim3(256), 0, stream>>>(Wg, F, flags, l, Bh, Bl);
    k_gemm<<<dim3(9, 13), dim3(256), 0, stream>>>(xh, xl, Bh, Bl, C);
    k_gat<<<dim3(1728), dim3(256), 0, stream>>>(C, csr_off, csr_src, bG, flags, l, xf, xh, xl);
  }
  k_final<<<dim3(8192), dim3(256), 0, stream>>>(src, seg, typ, word, post, segt, typt,
                                                gamma, beta, xf, flags, d_out);
}

// Round 7
// 485.582 us; speedup vs baseline: 1.3863x; 1.0610x over previous
//
#include <hip/hip_runtime.h>

// BertEmbedding + 5-layer GAT on MI355X (gfx950). Round 7:
//  - k_setup: fused detect+fold+nodes+csr (block-partitioned; flags derived
//    locally per block from 8 cached loads) -- removes 3 dispatch drains.
//  - k_prep_all: all 5 layers' B-matrix prep in one 780-block launch
//    (x-independent; per-layer Bh/Bl) -- off the per-layer critical path.
//  - k_final: nontemporal stores on the 98 MB streaming write.
//  - GEMM/GAT math byte-identical to passing round-6 kernel.
// Workspace ~18.4 MB (d_ws is ~300 MB per round-6 poison-fill evidence).

#define DEV __device__ __forceinline__

typedef short s16x8 __attribute__((ext_vector_type(8)));
typedef float f32x4 __attribute__((ext_vector_type(4)));

DEV float b2f(unsigned int u) { union { unsigned int i; float f; } v; v.i = u << 16; return v.f; }
DEV unsigned short f2b(float f) {
  union { float f; unsigned int i; } v; v.f = f;
  return (unsigned short)((v.i + 0x7fffu + ((v.i >> 16) & 1u)) >> 16);
}
DEV float gelu_exact(float x) { return 0.5f * x * (1.f + erff(x * 0.70710678118654752f)); }

// dual-dtype loads. fF: floats are f32 (else bf16). fI: ints are int64.
DEV float ldf(const void* p, size_t i, int fF) {
  return fF ? ((const float*)p)[i] : b2f(((const unsigned short*)p)[i]);
}
DEV int ldi(const void* p, size_t i, int fI) {
  return fI ? ((const int*)p)[2 * i] : ((const int*)p)[i];
}

// ---------------------------------------------------------------------------
// k_setup: fused front-end. Blocks 0..959: fold (F columns); 960..1535:
// nodes; 1536: CSR build. Every block derives dtype flags locally (wave 0,
// ~8 cached loads); block 0 persists them for later kernels.
// ---------------------------------------------------------------------------
__global__ __launch_bounds__(256) void k_setup(const void* __restrict__ src,
                                               const void* __restrict__ sst,
                                               const void* __restrict__ sen,
                                               const void* __restrict__ edge,
                                               const void* __restrict__ word,
                                               const void* __restrict__ pos,
                                               const void* __restrict__ aS,
                                               const void* __restrict__ aD,
                                               const void* __restrict__ Wg,
                                               float* __restrict__ F,
                                               unsigned short* __restrict__ xh,
                                               unsigned short* __restrict__ xl,
                                               int* __restrict__ csr_off,
                                               int* __restrict__ csr_src,
                                               int* __restrict__ flags) {
  __shared__ int sflags[2];
  __shared__ float sA[768], sD[768];
  __shared__ int cnt[576], off[577], fill[576];
  int t = threadIdx.x, bid = blockIdx.x;
  // --- local dtype detection (all blocks, wave 0) ---
  if (t < 64) {
    const unsigned short* w16 = (const unsigned short*)word;
    int crazy = 0;
    for (int i = t; i < 512; i += 64) {
      unsigned int e = (w16[i] >> 7) & 0xffu;
      if (e >= 135u || (e >= 1u && e <= 100u)) crazy++;
    }
#pragma unroll
    for (int o = 32; o > 0; o >>= 1) crazy += __shfl_down(crazy, o);
    if (t == 0) {
      sflags[0] = (crazy >= 8) ? 1 : 0;
      sflags[1] = (((const int*)pos)[1] == 0) ? 1 : 0;
    }
  }
  __syncthreads();
  int fF = sflags[0], fI = sflags[1];
  if (bid == 0 && t == 0) { flags[0] = fF; flags[1] = fI; }

  if (bid < 960) {
    // ---- fold: F[l][j][k], wave-per-row ----
    int R0 = bid * 4;
    int l = R0 / 768;
    for (int i = t; i < 768; i += 256) {
      sA[i] = ldf(aS, (size_t)l * 768 + i, fF);
      sD[i] = ldf(aD, (size_t)l * 768 + i, fF);
    }
    __syncthreads();
    int wave = t >> 6, lane = t & 63;
    int k = (R0 + wave) - l * 768;
    size_t wbase = ((size_t)l * 768 + k) * 768;
    float accS[4] = {0.f, 0.f, 0.f, 0.f}, accD[4] = {0.f, 0.f, 0.f, 0.f};
#pragma unroll
    for (int i = 0; i < 12; ++i) {
      int d = lane + 64 * i;
      float w = ldf(Wg, wbase + d, fF);
      accS[i / 3] += w * sA[d];
      accD[i / 3] += w * sD[d];
    }
    float* Fl = F + (size_t)l * 8 * 768;
#pragma unroll
    for (int h = 0; h < 4; ++h) {
      float sS = accS[h], sDv = accD[h];
#pragma unroll
      for (int o = 32; o > 0; o >>= 1) {
        sS += __shfl_down(sS, o);
        sDv += __shfl_down(sDv, o);
      }
      if (lane == 0) {
        Fl[(size_t)h * 768 + k] = sS;
        Fl[(size_t)(4 + h) * 768 + k] = sDv;
      }
    }
  } else if (bid < 1536) {
    // ---- nodes: CLS emb / span sums -> split bf16 ----
    int g = bid - 960;
    int b = g / 9, j = g % 9;
    float v[3] = {0.f, 0.f, 0.f};
    if (j == 0) {
      int r = ldi(src, (size_t)b * 512, fI);
#pragma unroll
      for (int ii = 0; ii < 3; ++ii) v[ii] = ldf(word, (size_t)r * 768 + t + 256 * ii, fF);
    } else {
      int st = ldi(sst, (size_t)b * 8 + j - 1, fI);
      int en = ldi(sen, (size_t)b * 8 + j - 1, fI);
      for (int s = st; s <= en; ++s) {
        int r = ldi(src, (size_t)b * 512 + s, fI);
#pragma unroll
        for (int ii = 0; ii < 3; ++ii) v[ii] += ldf(word, (size_t)r * 768 + t + 256 * ii, fF);
      }
    }
#pragma unroll
    for (int ii = 0; ii < 3; ++ii) {
      float g0 = v[ii];
      unsigned short hi = f2b(g0);
      size_t o = (size_t)g * 768 + t + 256 * ii;
      xh[o] = hi;
      xl[o] = f2b(g0 - b2f((unsigned int)hi));
    }
  } else {
    // ---- CSR: symmetrized edges + self loops, by dst ----
    for (int i = t; i < 576; i += 256) cnt[i] = 0;
    __syncthreads();
    for (int e = t; e < 8768; e += 256) {
      int di;
      if (e < 4096) di = ldi(edge, (size_t)4096 + e, fI);
      else if (e < 8192) di = ldi(edge, (size_t)e - 4096, fI);
      else di = e - 8192;
      atomicAdd(&cnt[di], 1);
    }
    __syncthreads();
    if (t == 0) {
      int a = 0;
      for (int i = 0; i < 576; ++i) { off[i] = a; a += cnt[i]; }
      off[576] = a;
    }
    __syncthreads();
    for (int i = t; i < 577; i += 256) csr_off[i] = off[i];
    for (int i = t; i < 576; i += 256) fill[i] = off[i];
    __syncthreads();
    for (int e = t; e < 8768; e += 256) {
      int si, di;
      if (e < 4096)      { si = ldi(edge, (size_t)e, fI); di = ldi(edge, (size_t)4096 + e, fI); }
      else if (e < 8192) { si = ldi(edge, (size_t)e, fI); di = ldi(edge, (size_t)e - 4096, fI); }
      else               { si = e - 8192;                 di = si; }
      int p = atomicAdd(&fill[di], 1);
      csr_src[p] = si;
    }
  }
}

// ---------------------------------------------------------------------------
// k_prep_all: all 5 layers' MFMA B matrices: Bh/Bl bf16, [l][n 832][k 768].
// n<768: W[l][k][n] split hi/lo; 768..775: F[l][n-768][k]; >=776: 0.
// 780 blocks = 5 layers x (12 kt x 13 nt), 64x64 LDS-transposed tiles.
// ---------------------------------------------------------------------------
__global__ __launch_bounds__(256) void k_prep_all(const void* __restrict__ Wg,
                                                  const float* __restrict__ F,
                                                  const int* __restrict__ flg,
                                                  unsigned short* __restrict__ Bh,
                                                  unsigned short* __restrict__ Bl) {
  int fF = flg[0];
  __shared__ float tile[64][65];
  int bid = blockIdx.x, t = threadIdx.x;
  int layer = bid / 156, r = bid % 156;
  int kt = r / 13, nt = r % 13;
  int k0 = kt * 64, n0 = nt * 64;
#pragma unroll
  for (int i = 0; i < 16; ++i) {
    int e = t + 256 * i, rk = e >> 6, cn = e & 63;
    float v;
    if (nt < 12) {
      v = ldf(Wg, ((size_t)layer * 768 + k0 + rk) * 768 + n0 + cn, fF);
    } else {
      v = (cn < 8) ? F[(size_t)layer * 8 * 768 + (size_t)cn * 768 + k0 + rk] : 0.f;
    }
    tile[rk][cn] = v;
  }
  __syncthreads();
  size_t lbase = (size_t)layer * 832 * 768;
#pragma unroll
  for (int i = 0; i < 16; ++i) {
    int e = t + 256 * i, rn = e >> 6, ck = e & 63;
    float v = tile[ck][rn];
    unsigned short hi = f2b(v);
    float lo = v - b2f((unsigned int)hi);
    size_t o = lbase + (size_t)(n0 + rn) * 768 + k0 + ck;
    Bh[o] = hi;
    Bl[o] = f2b(lo);
  }
}

// ---------------------------------------------------------------------------
// k_gemm: C[576x832] = x @ B^T via MFMA 16x16x32 bf16, split emulation
// acc = xh*Bh + xh*Bl + xl*Bh. Block = 64x64 tile, 4 waves. Grid (9, 13).
// ---------------------------------------------------------------------------
__global__ __launch_bounds__(256) void k_gemm(const unsigned short* __restrict__ xh,
                                              const unsigned short* __restrict__ xl,
                                              const unsigned short* __restrict__ Bh,
                                              const unsigned short* __restrict__ Bl,
                                              float* __restrict__ C) {
  __shared__ __align__(16) unsigned short Ah[64][48];
  __shared__ __align__(16) unsigned short Al[64][48];
  __shared__ __align__(16) unsigned short Bhs[64][48];
  __shared__ __align__(16) unsigned short Bls[64][48];
  int t = threadIdx.x;
  int rt = blockIdx.x, ct = blockIdx.y;
  int wave = t >> 6, lane = t & 63, quad = lane >> 4, lr = lane & 15;
  f32x4 acc[4];
#pragma unroll
  for (int c = 0; c < 4; ++c) acc[c] = (f32x4){0.f, 0.f, 0.f, 0.f};
  int sr = t >> 2, sc = t & 3;
  const uint4* Agh = (const uint4*)(xh + (size_t)(rt * 64 + sr) * 768);
  const uint4* Agl = (const uint4*)(xl + (size_t)(rt * 64 + sr) * 768);
  const uint4* Bgh = (const uint4*)(Bh + (size_t)(ct * 64 + sr) * 768);
  const uint4* Bgl = (const uint4*)(Bl + (size_t)(ct * 64 + sr) * 768);
  for (int kk = 0; kk < 24; ++kk) {
    *(uint4*)&Ah[sr][sc * 8] = Agh[kk * 4 + sc];
    *(uint4*)&Al[sr][sc * 8] = Agl[kk * 4 + sc];
    *(uint4*)&Bhs[sr][sc * 8] = Bgh[kk * 4 + sc];
    *(uint4*)&Bls[sr][sc * 8] = Bgl[kk * 4 + sc];
    __syncthreads();
    s16x8 ah = *(const s16x8*)&Ah[wave * 16 + lr][quad * 8];
    s16x8 al = *(const s16x8*)&Al[wave * 16 + lr][quad * 8];
#pragma unroll
    for (int c = 0; c < 4; ++c) {
      s16x8 bh = *(const s16x8*)&Bhs[c * 16 + lr][quad * 8];
      s16x8 bl = *(const s16x8*)&Bls[c * 16 + lr][quad * 8];
      acc[c] = __builtin_amdgcn_mfma_f32_16x16x32_bf16(ah, bh, acc[c], 0, 0, 0);
      acc[c] = __builtin_amdgcn_mfma_f32_16x16x32_bf16(ah, bl, acc[c], 0, 0, 0);
      acc[c] = __builtin_amdgcn_mfma_f32_16x16x32_bf16(al, bh, acc[c], 0, 0, 0);
    }
    __syncthreads();
  }
  int row0 = rt * 64 + wave * 16 + quad * 4;
  int col0 = ct * 64 + lr;
#pragma unroll
  for (int c = 0; c < 4; ++c)
#pragma unroll
    for (int r = 0; r < 4; ++r)
      C[(size_t)(row0 + r) * 832 + col0 + c * 16] = acc[c][r];
}

// ---------------------------------------------------------------------------
// k_gat: one thread per (node, feature). Logit clamped -> finite. Writes xf
// (f32) + split-bf16 xh/xl for the next layer's GEMM.
// ---------------------------------------------------------------------------
__global__ __launch_bounds__(256) void k_gat(const float* __restrict__ C,
                                             const int* __restrict__ off,
                                             const int* __restrict__ srcs,
                                             const void* __restrict__ bG,
                                             const int* __restrict__ flg,
                                             int layer,
                                             float* __restrict__ xf,
                                             unsigned short* __restrict__ xh,
                                             unsigned short* __restrict__ xl) {
  int fF = flg[0];
  int idx = blockIdx.x * 256 + threadIdx.x;  // 576*768
  int n = idx / 768, d = idx - n * 768, h = d / 192;
  float aDv = C[(size_t)n * 832 + 772 + h];
  int e0 = off[n], e1 = off[n + 1];
  float num = 0.f, den = 0.f;
  for (int e = e0; e < e1; ++e) {
    int s = srcs[e];
    float lg = C[(size_t)s * 832 + 768 + h] + aDv;
    float lrel = lg < 0.f ? 0.2f * lg : lg;
    lrel = fminf(fmaxf(lrel, -60.f), 40.f);
    float w = __expf(lrel);
    num += w * C[(size_t)s * 832 + d];
    den += w;
  }
  float g = gelu_exact(num / den + ldf(bG, (size_t)layer * 768 + d, fF));
  xf[idx] = g;
  unsigned short hi = f2b(g);
  xh[idx] = hi;
  xl[idx] = f2b(g - b2f((unsigned int)hi));
}

// ---------------------------------------------------------------------------
// k_final: emb = (CLS? gnn_x : word[src]) + pos[s] + seg + type; LayerNorm.
// Wave-per-row, float4, nontemporal streaming stores (98 MB write).
// ---------------------------------------------------------------------------
__global__ __launch_bounds__(256) void k_final(const void* __restrict__ src,
                                               const void* __restrict__ seg,
                                               const void* __restrict__ typ,
                                               const void* __restrict__ word,
                                               const void* __restrict__ post,
                                               const void* __restrict__ segt,
                                               const void* __restrict__ typt,
                                               const void* __restrict__ gamma,
                                               const void* __restrict__ beta,
                                               const float* __restrict__ xf,
                                               const int* __restrict__ flg,
                                               void* __restrict__ out) {
  int fF = flg[0], fI = flg[1];
  int wave = threadIdx.x >> 6, lane = threadIdx.x & 63;
  int r = blockIdx.x * 4 + wave;
  int b = r >> 9, s = r & 511;
  int sg = ldi(seg, (size_t)r, fI), tp = ldi(typ, (size_t)r, fI);
  int wrow = ldi(src, (size_t)r, fI);
  bool cls = (s == 0);
  float sum = 0.f, sq = 0.f;
  f32x4 vv[3];
  float vs[12];
  if (fF) {
    const f32x4* wr = (const f32x4*)((const float*)word + (size_t)wrow * 768);
    const f32x4* pr = (const f32x4*)((const float*)post + (size_t)s * 768);
    const f32x4* sr = (const f32x4*)((const float*)segt + (size_t)sg * 768);
    const f32x4* tr = (const f32x4*)((const float*)typt + (size_t)tp * 768);
    const f32x4* xr = (const f32x4*)(xf + (size_t)b * 9 * 768);
#pragma unroll
    for (int j = 0; j < 3; ++j) {
      int p = lane + 64 * j;
      f32x4 a = cls ? xr[p] : wr[p];
      a += pr[p]; a += sr[p]; a += tr[p];
      vv[j] = a;
#pragma unroll
      for (int c = 0; c < 4; ++c) { sum += a[c]; sq += a[c] * a[c]; }
    }
  } else {
#pragma unroll
    for (int j = 0; j < 12; ++j) {
      int d = lane + 64 * j;
      float xv = cls ? xf[(size_t)b * 9 * 768 + d] : ldf(word, (size_t)wrow * 768 + d, fF);
      xv += ldf(post, (size_t)s * 768 + d, fF);
      xv += ldf(segt, (size_t)sg * 768 + d, fF);
      xv += ldf(typt, (size_t)tp * 768 + d, fF);
      vs[j] = xv;
      sum += xv; sq += xv * xv;
    }
  }
#pragma unroll
  for (int o = 32; o > 0; o >>= 1) { sum += __shfl_down(sum, o); sq += __shfl_down(sq, o); }
  sum = __shfl(sum, 0); sq = __shfl(sq, 0);
  float mu = sum * (1.f / 768.f);
  float var = fmaxf(sq * (1.f / 768.f) - mu * mu, 0.f);
  float rstd = rsqrtf(var + 1e-6f);
  if (fF) {
    const f32x4* gm = (const f32x4*)gamma;
    const f32x4* bt = (const f32x4*)beta;
    f32x4* orow = (f32x4*)((float*)out + (size_t)r * 768);
#pragma unroll
    for (int j = 0; j < 3; ++j) {
      int p = lane + 64 * j;
      f32x4 g4 = gm[p], b4 = bt[p], y;
#pragma unroll
      for (int c = 0; c < 4; ++c) y[c] = g4[c] * (vv[j][c] - mu) * rstd + b4[c];
      __builtin_nontemporal_store(y, &orow[p]);
    }
  } else {
#pragma unroll
    for (int j = 0; j < 12; ++j) {
      int d = lane + 64 * j;
      float y = ldf(gamma, (size_t)d, fF) * (vs[j] - mu) * rstd + ldf(beta, (size_t)d, fF);
      ((unsigned short*)out)[(size_t)r * 768 + d] = f2b(y);
    }
  }
}

extern "C" void kernel_launch(void* const* d_in, const int* in_sizes, int n_in,
                              void* d_out, int out_size, void* d_ws, size_t ws_size,
                              hipStream_t stream) {
  const void* src  = d_in[0];
  const void* seg  = d_in[1];
  const void* typ  = d_in[2];
  const void* pos  = d_in[3];
  const void* sst  = d_in[4];
  const void* sen  = d_in[5];
  const void* edge = d_in[6];
  const void* word = d_in[7];
  const void* post = d_in[8];
  const void* segt = d_in[9];
  const void* typt = d_in[10];
  const void* gamma = d_in[11];
  const void* beta  = d_in[12];
  const void* Wg    = d_in[13];
  const void* aS    = d_in[14];
  const void* aD    = d_in[15];
  const void* bG    = d_in[16];

  char* ws = (char*)d_ws;
  float* xf = (float*)(ws);                               //  1,769,472
  float* C  = (float*)(ws + 1769472);                     //  1,916,928
  unsigned short* xh = (unsigned short*)(ws + 3686400);   //    884,736
  unsigned short* xl = (unsigned short*)(ws + 4571136);   //    884,736
  unsigned short* Bh = (unsigned short*)(ws + 5455872);   //  6,389,760 (5 layers)
  unsigned short* Bl = (unsigned short*)(ws + 11845632);  //  6,389,760
  float* F = (float*)(ws + 18235392);                     //    122,880
  int* csr_off = (int*)(ws + 18358272);                   //      2,320 (pad)
  int* csr_src = (int*)(ws + 18360592);                   //     35,072
  int* flags   = (int*)(ws + 18395664);                   //          8

  k_setup<<<dim3(1537), dim3(256), 0, stream>>>(src, sst, sen, edge, word, pos, aS, aD, Wg,
                                                F, xh, xl, csr_off, csr_src, flags);
  k_prep_all<<<dim3(780), dim3(256), 0, stream>>>(Wg, F, flags, Bh, Bl);
  for (int l = 0; l < 5; ++l) {
    k_gemm<<<dim3(9, 13), dim3(256), 0, stream>>>(xh, xl,
                                                  Bh + (size_t)l * 832 * 768,
                                                  Bl + (size_t)l * 832 * 768, C);
    k_gat<<<dim3(1728), dim3(256), 0, stream>>>(C, csr_off, csr_src, bG, flags, l, xf, xh, xl);
  }
  k_final<<<dim3(8192), dim3(256), 0, stream>>>(src, seg, typ, word, post, segt, typt,
                                                gamma, beta, xf, flags, d_out);
}